// Round 1
// baseline (3388.122 us; speedup 1.0000x reference)
//
#include <hip/hip_runtime.h>
#include <hip/hip_bf16.h>

// GCPNet update: two chained edge-gated graph convs (GCAO) with training-mode BN.
// Sizes fixed per reference: N=20000 atoms, E=200000 bonds, A=600000 angles, D=128.

typedef float f32x4 __attribute__((ext_vector_type(4)));
typedef short s16x8 __attribute__((ext_vector_type(8)));
typedef unsigned short u16;

__device__ __forceinline__ u16 f2bf(float f){
  union { float f; unsigned u; } v; v.f = f;
  unsigned u = v.u;
  return (u16)((u + 0x7FFFu + ((u >> 16) & 1u)) >> 16);   // RNE
}
__device__ __forceinline__ float bf2f(u16 h){
  union { unsigned u; float f; } v; v.u = ((unsigned)h) << 16; return v.f;
}
__device__ __forceinline__ float sigmoidf_(float x){ return 1.0f / (1.0f + __expf(-x)); }
__device__ __forceinline__ float siluf_(float x){ return x / (1.0f + __expf(-x)); }

// ---------------- weight pack into MFMA A-fragment order ----------------
// wpack[mat][t][ks][lane][j] = W[mat][k = ks*32 + (lane>>4)*8 + j][n = t*16 + (lane&15)]
// (A-operand = W^T tile: lane m-index = W col, so D^T gives lane 4 consecutive out-cols)
__global__ __launch_bounds__(256) void pack_w_kernel(
    const float* __restrict__ Wba, const float* __restrict__ Wab, u16* __restrict__ wpack){
  int idx = blockIdx.x * 256 + threadIdx.x;      // 10 * 16384 entries
  int mat = idx >> 14;
  int r = idx & 16383;
  int j = r & 7, lane = (r >> 3) & 63, ks = (r >> 9) & 3, t = r >> 11;
  int k = ks * 32 + ((lane >> 4) << 3) + j;
  int n = t * 16 + (lane & 15);
  const float* W = (mat < 5) ? (Wba + (size_t)mat * 16384) : (Wab + (size_t)(mat - 5) * 16384);
  wpack[idx] = f2bf(W[k * 128 + n]);
}

// ---------------- fused x-side matmul: L{0,1,3,4} = x @ W{0,1,3,4} + b ----------------
__global__ __launch_bounds__(256) void xmm_kernel(
    const float* __restrict__ x, int nrows,
    const u16* __restrict__ wpackL, const float* __restrict__ bias,
    u16* __restrict__ L0, u16* __restrict__ L1, u16* __restrict__ L3, u16* __restrict__ L4){
  __shared__ u16 wlds[16384];
  const int tid = threadIdx.x;
  const int lane = tid & 63, wv = tid >> 6;
  const int g = lane >> 4;
  const long row = (long)blockIdx.x * 64 + wv * 16 + (lane & 15);
  const bool valid = row < nrows;
  const long rc = valid ? row : (long)(nrows - 1);

  s16x8 xf[4];
  {
    const float* xr = x + rc * 128 + g * 8;
    #pragma unroll
    for (int ks = 0; ks < 4; ++ks){
      float4 a = *(const float4*)(xr + ks * 32);
      float4 b = *(const float4*)(xr + ks * 32 + 4);
      s16x8 f;
      f[0]=(short)f2bf(a.x); f[1]=(short)f2bf(a.y); f[2]=(short)f2bf(a.z); f[3]=(short)f2bf(a.w);
      f[4]=(short)f2bf(b.x); f[5]=(short)f2bf(b.y); f[6]=(short)f2bf(b.z); f[7]=(short)f2bf(b.w);
      xf[ks] = f;
    }
  }
  u16* outs[4] = {L0, L1, L3, L4};
  const int mats[4] = {0, 1, 3, 4};
  #pragma unroll
  for (int mi = 0; mi < 4; ++mi){
    const int mat = mats[mi];
    __syncthreads();
    { const uint4* s = (const uint4*)(wpackL + (size_t)mat * 16384);
      uint4* d = (uint4*)wlds;
      #pragma unroll
      for (int i = 0; i < 8; ++i) d[i * 256 + tid] = s[i * 256 + tid];
    }
    __syncthreads();
    u16* Lout = outs[mi];
    #pragma unroll
    for (int t = 0; t < 8; ++t){
      f32x4 acc = {0.f, 0.f, 0.f, 0.f};
      #pragma unroll
      for (int ks = 0; ks < 4; ++ks){
        s16x8 wf = *(const s16x8*)(wlds + (t * 4 + ks) * 512 + lane * 8);
        acc = __builtin_amdgcn_mfma_f32_16x16x32_bf16(wf, xf[ks], acc, 0, 0, 0);
      }
      const int c0 = t * 16 + g * 4;
      float4 bv = *(const float4*)(bias + mat * 128 + c0);
      if (valid){
        ushort4 o;
        o.x = f2bf(acc[0] + bv.x); o.y = f2bf(acc[1] + bv.y);
        o.z = f2bf(acc[2] + bv.z); o.w = f2bf(acc[3] + bv.w);
        *(ushort4*)(Lout + row * 128 + c0) = o;
      }
    }
  }
}

// ------- fused y-matmul + gather + gate + scatter: m, sigma, num/den atomics -------
__global__ __launch_bounds__(256) void edge_kernel(
    const float* __restrict__ y, int E,
    const int* __restrict__ srcIdx, const int* __restrict__ dstIdx,
    const u16* __restrict__ wpack2, const float* __restrict__ bias2,
    const u16* __restrict__ L0, const u16* __restrict__ L1, const u16* __restrict__ L3,
    u16* __restrict__ Mout, float* __restrict__ num, float* __restrict__ den){
  __shared__ u16 wlds[16384];
  const int tid = threadIdx.x;
  { const uint4* s = (const uint4*)wpack2;
    uint4* d = (uint4*)wlds;
    #pragma unroll
    for (int i = 0; i < 8; ++i) d[i * 256 + tid] = s[i * 256 + tid];
  }
  const int lane = tid & 63, wv = tid >> 6;
  const int g = lane >> 4;
  const int e = blockIdx.x * 64 + wv * 16 + (lane & 15);   // E multiple of 64
  const int src = srcIdx[e];
  const int dst = dstIdx[e];
  s16x8 yf[4];
  {
    const float* yr = y + (size_t)e * 128 + g * 8;
    #pragma unroll
    for (int ks = 0; ks < 4; ++ks){
      float4 a = *(const float4*)(yr + ks * 32);
      float4 b = *(const float4*)(yr + ks * 32 + 4);
      s16x8 f;
      f[0]=(short)f2bf(a.x); f[1]=(short)f2bf(a.y); f[2]=(short)f2bf(a.z); f[3]=(short)f2bf(a.w);
      f[4]=(short)f2bf(b.x); f[5]=(short)f2bf(b.y); f[6]=(short)f2bf(b.z); f[7]=(short)f2bf(b.w);
      yf[ks] = f;
    }
  }
  __syncthreads();
  #pragma unroll
  for (int t = 0; t < 8; ++t){
    f32x4 acc = {0.f, 0.f, 0.f, 0.f};
    #pragma unroll
    for (int ks = 0; ks < 4; ++ks){
      s16x8 wf = *(const s16x8*)(wlds + (t * 4 + ks) * 512 + lane * 8);
      acc = __builtin_amdgcn_mfma_f32_16x16x32_bf16(wf, yf[ks], acc, 0, 0, 0);
    }
    const int c0 = t * 16 + g * 4;
    float4 bv = *(const float4*)(bias2 + c0);
    ushort4 l0 = *(const ushort4*)(L0 + (size_t)src * 128 + c0);
    ushort4 l1 = *(const ushort4*)(L1 + (size_t)dst * 128 + c0);
    ushort4 l3 = *(const ushort4*)(L3 + (size_t)src * 128 + c0);
    float* nb = num + (size_t)dst * 128 + c0;
    float* db = den + (size_t)dst * 128 + c0;
    ushort4 mo;
    float mv, sg, bh;
    mv = acc[0] + bv.x + bf2f(l0.x) + bf2f(l1.x); sg = sigmoidf_(mv); bh = bf2f(l3.x) * sg;
    mo.x = f2bf(mv); atomicAdd(nb + 0, bh); atomicAdd(db + 0, sg);
    mv = acc[1] + bv.y + bf2f(l0.y) + bf2f(l1.y); sg = sigmoidf_(mv); bh = bf2f(l3.y) * sg;
    mo.y = f2bf(mv); atomicAdd(nb + 1, bh); atomicAdd(db + 1, sg);
    mv = acc[2] + bv.z + bf2f(l0.z) + bf2f(l1.z); sg = sigmoidf_(mv); bh = bf2f(l3.z) * sg;
    mo.z = f2bf(mv); atomicAdd(nb + 2, bh); atomicAdd(db + 2, sg);
    mv = acc[3] + bv.w + bf2f(l0.w) + bf2f(l1.w); sg = sigmoidf_(mv); bh = bf2f(l3.w) * sg;
    mo.w = f2bf(mv); atomicAdd(nb + 3, bh); atomicAdd(db + 3, sg);
    *(ushort4*)(Mout + (size_t)e * 128 + c0) = mo;
  }
}

// ---------------- per-column stats over bf16 matrix m ----------------
__global__ __launch_bounds__(256) void colstats_kernel(
    const u16* __restrict__ M, int rows, float* __restrict__ sum, float* __restrict__ sumsq){
  const int tid = threadIdx.x;
  const int c2 = (tid & 63) * 2, rg = tid >> 6;
  float s0=0,ss0=0,s1=0,ss1=0;
  for (long r = blockIdx.x * 4 + rg; r < rows; r += (long)gridDim.x * 4){
    ushort2 v = *(const ushort2*)(M + r * 128 + c2);
    float a = bf2f(v.x), b = bf2f(v.y);
    s0 += a; ss0 += a*a; s1 += b; ss1 += b*b;
  }
  __shared__ float sh[1024];
  sh[tid] = s0; sh[256+tid] = ss0; sh[512+tid] = s1; sh[768+tid] = ss1;
  __syncthreads();
  if (rg == 0){
    int c = tid & 63;
    float S0=0,SS0=0,S1=0,SS1=0;
    #pragma unroll
    for (int q = 0; q < 4; ++q){ int t2 = q*64 + c; S0+=sh[t2]; SS0+=sh[256+t2]; S1+=sh[512+t2]; SS1+=sh[768+t2]; }
    atomicAdd(&sum[c2], S0);   atomicAdd(&sumsq[c2], SS0);
    atomicAdd(&sum[c2+1], S1); atomicAdd(&sumsq[c2+1], SS1);
  }
}

// -------- h = L4 + num/(den+eps); overwrite num with h; node BN stats --------
__global__ __launch_bounds__(256) void node_h_kernel(
    const u16* __restrict__ L4, float* __restrict__ num, const float* __restrict__ den,
    int n, float* __restrict__ sum, float* __restrict__ sumsq){
  const int tid = threadIdx.x;
  const int c2 = (tid & 63) * 2, rg = tid >> 6;
  float s0=0,ss0=0,s1=0,ss1=0;
  for (long r = blockIdx.x * 4 + rg; r < n; r += (long)gridDim.x * 4){
    const long bi = r * 128 + c2;
    float2 nu = *(float2*)(num + bi);
    float2 de = *(const float2*)(den + bi);
    ushort2 l4 = *(const ushort2*)(L4 + bi);
    float h0 = bf2f(l4.x) + nu.x / (de.x + 1e-6f);
    float h1 = bf2f(l4.y) + nu.y / (de.y + 1e-6f);
    *(float2*)(num + bi) = make_float2(h0, h1);
    s0 += h0; ss0 += h0*h0; s1 += h1; ss1 += h1*h1;
  }
  __shared__ float sh[1024];
  sh[tid] = s0; sh[256+tid] = ss0; sh[512+tid] = s1; sh[768+tid] = ss1;
  __syncthreads();
  if (rg == 0){
    int c = tid & 63;
    float S0=0,SS0=0,S1=0,SS1=0;
    #pragma unroll
    for (int q = 0; q < 4; ++q){ int t2 = q*64 + c; S0+=sh[t2]; SS0+=sh[256+t2]; S1+=sh[512+t2]; SS1+=sh[768+t2]; }
    atomicAdd(&sum[c2], S0);   atomicAdd(&sumsq[c2], SS0);
    atomicAdd(&sum[c2+1], S1); atomicAdd(&sumsq[c2+1], SS1);
  }
}

// ---------------- out = base + silu(BN(h)) ; h fp32 ----------------
__global__ __launch_bounds__(256) void apply_f32_kernel(
    const float* __restrict__ base, const float* __restrict__ h, int n,
    const float* __restrict__ sum, const float* __restrict__ sumsq,
    const float* __restrict__ gamma, const float* __restrict__ beta,
    float* __restrict__ out){
  const int tid = threadIdx.x;
  const int c2 = (tid & 63) * 2, rg = tid >> 6;
  const float invn = 1.0f / (float)n;
  float m0 = sum[c2] * invn, m1 = sum[c2+1] * invn;
  float v0 = sumsq[c2] * invn - m0*m0, v1 = sumsq[c2+1] * invn - m1*m1;
  float sc0 = gamma[c2]   * rsqrtf(v0 + 1e-5f);
  float sc1 = gamma[c2+1] * rsqrtf(v1 + 1e-5f);
  float sh0 = beta[c2]   - m0 * sc0;
  float sh1 = beta[c2+1] - m1 * sc1;
  for (long r = blockIdx.x * 4 + rg; r < n; r += (long)gridDim.x * 4){
    const long bi = r * 128 + c2;
    float2 hv = *(const float2*)(h + bi);
    float2 xv = *(const float2*)(base + bi);
    float a = hv.x * sc0 + sh0, b = hv.y * sc1 + sh1;
    *(float2*)(out + bi) = make_float2(xv.x + siluf_(a), xv.y + siluf_(b));
  }
}

// ---------------- out = base + silu(BN(m)) ; m bf16 (in-place safe) ----------------
__global__ __launch_bounds__(256) void apply_bf16_kernel(
    const float* __restrict__ base, const u16* __restrict__ m, int n,
    const float* __restrict__ sum, const float* __restrict__ sumsq,
    const float* __restrict__ gamma, const float* __restrict__ beta,
    float* __restrict__ out){
  const int tid = threadIdx.x;
  const int c2 = (tid & 63) * 2, rg = tid >> 6;
  const float invn = 1.0f / (float)n;
  float m0 = sum[c2] * invn, m1 = sum[c2+1] * invn;
  float v0 = sumsq[c2] * invn - m0*m0, v1 = sumsq[c2+1] * invn - m1*m1;
  float sc0 = gamma[c2]   * rsqrtf(v0 + 1e-5f);
  float sc1 = gamma[c2+1] * rsqrtf(v1 + 1e-5f);
  float sh0 = beta[c2]   - m0 * sc0;
  float sh1 = beta[c2+1] - m1 * sc1;
  for (long r = blockIdx.x * 4 + rg; r < n; r += (long)gridDim.x * 4){
    const long bi = r * 128 + c2;
    ushort2 mv = *(const ushort2*)(m + bi);
    float2 xv = *(const float2*)(base + bi);
    float a = bf2f(mv.x) * sc0 + sh0, b = bf2f(mv.y) * sc1 + sh1;
    *(float2*)(out + bi) = make_float2(xv.x + siluf_(a), xv.y + siluf_(b));
  }
}

extern "C" void kernel_launch(void* const* d_in, const int* in_sizes, int n_in,
                              void* d_out, int out_size, void* d_ws, size_t ws_size,
                              hipStream_t stream){
  const float* atom = (const float*)d_in[0];
  const float* bond = (const float*)d_in[1];
  const float* trip = (const float*)d_in[2];
  const int*   eidx = (const int*)d_in[3];   // [2][E]
  const int*   aidx = (const int*)d_in[4];   // [2][A]
  const float* Wba  = (const float*)d_in[5];
  const float* bba  = (const float*)d_in[6];
  const float* bnba = (const float*)d_in[7];
  const float* Wab  = (const float*)d_in[8];
  const float* bab  = (const float*)d_in[9];
  const float* bnab = (const float*)d_in[10];

  const int N = 20000, E = 200000, A = 600000;

  float* out_atom = (float*)d_out;
  float* out_bond = out_atom + (size_t)N * 128;
  float* out_trip = out_bond + (size_t)E * 128;

  char* ws = (char*)d_ws;
  u16* wpack = (u16*)ws;                                   // 10*16384*2 = 327680 B
  float* stats = (float*)(ws + 327680);                    // 4*128 f32
  float* sum_e = stats, *sumsq_e = stats + 128, *sum_n = stats + 256, *sumsq_n = stats + 384;
  size_t off = 329728;
  u16* L0 = (u16*)(ws + off); off += (size_t)E * 128 * 2;
  u16* L1 = (u16*)(ws + off); off += (size_t)E * 128 * 2;
  u16* L3 = (u16*)(ws + off); off += (size_t)E * 128 * 2;
  u16* L4 = (u16*)(ws + off); off += (size_t)E * 128 * 2;
  u16* M  = (u16*)(ws + off); off += (size_t)A * 128 * 2;
  float* num = (float*)(ws + off); off += (size_t)E * 128 * 4;
  float* den = (float*)(ws + off); off += (size_t)E * 128 * 4;
  // total ws use ~537.5 MiB

  pack_w_kernel<<<640, 256, 0, stream>>>(Wba, Wab, wpack);

  // ---- phase 1: line graph. x = bond [E,128], edges = angle_index (A), y = trip ----
  hipMemsetAsync(num, 0, (size_t)E * 128 * 8, stream);     // num + den (contiguous)
  hipMemsetAsync(stats, 0, 2048, stream);
  xmm_kernel<<<E / 64, 256, 0, stream>>>(bond, E, wpack, bba, L0, L1, L3, L4);
  edge_kernel<<<A / 64, 256, 0, stream>>>(trip, A, aidx, aidx + A, wpack + 2 * 16384,
                                          bba + 256, L0, L1, L3, M, num, den);
  colstats_kernel<<<1024, 256, 0, stream>>>(M, A, sum_e, sumsq_e);
  node_h_kernel<<<1024, 256, 0, stream>>>(L4, num, den, E, sum_n, sumsq_n);
  // bond_intermediate -> d_out bond slot (phase 2 reads + updates it in place)
  apply_f32_kernel<<<2048, 256, 0, stream>>>(bond, num, E, sum_n, sumsq_n, bnba, bnba + 128, out_bond);
  apply_bf16_kernel<<<2048, 256, 0, stream>>>(trip, M, A, sum_e, sumsq_e, bnba + 256, bnba + 384, out_trip);

  // ---- phase 2: atom graph. x = atom [N,128], edges = edge_index (E), y = bond_intermediate ----
  hipMemsetAsync(num, 0, (size_t)N * 128 * 4, stream);
  hipMemsetAsync(den, 0, (size_t)N * 128 * 4, stream);
  hipMemsetAsync(stats, 0, 2048, stream);
  xmm_kernel<<<(N + 63) / 64, 256, 0, stream>>>(atom, N, wpack + 5 * 16384, bab, L0, L1, L3, L4);
  edge_kernel<<<E / 64, 256, 0, stream>>>(out_bond, E, eidx, eidx + E, wpack + 7 * 16384,
                                          bab + 256, L0, L1, L3, M, num, den);
  colstats_kernel<<<1024, 256, 0, stream>>>(M, E, sum_e, sumsq_e);
  node_h_kernel<<<1024, 256, 0, stream>>>(L4, num, den, N, sum_n, sumsq_n);
  apply_f32_kernel<<<2048, 256, 0, stream>>>(atom, num, N, sum_n, sumsq_n, bnab, bnab + 128, out_atom);
  apply_bf16_kernel<<<2048, 256, 0, stream>>>(out_bond, M, E, sum_e, sumsq_e, bnab + 256, bnab + 384, out_bond);
}

// Round 2
// 1459.620 us; speedup vs baseline: 2.3212x; 2.3212x over previous
//
#include <hip/hip_runtime.h>
#include <hip/hip_bf16.h>

// GCPNet update: two chained edge-gated graph convs (GCAO) with training-mode BN.
// Sizes fixed per reference: N=20000 atoms, E=200000 bonds, A=600000 angles, D=128.
// R2: replaced scattered fp32 atomics (segment_sum) with CSR build + gather-side
// aggregation. Edge kernel now only does y-matmul + L0/L1 gather + M write.

typedef float f32x4 __attribute__((ext_vector_type(4)));
typedef short s16x8 __attribute__((ext_vector_type(8)));
typedef unsigned short u16;

__device__ __forceinline__ u16 f2bf(float f){
  union { float f; unsigned u; } v; v.f = f;
  unsigned u = v.u;
  return (u16)((u + 0x7FFFu + ((u >> 16) & 1u)) >> 16);   // RNE
}
__device__ __forceinline__ float bf2f(u16 h){
  union { unsigned u; float f; } v; v.u = ((unsigned)h) << 16; return v.f;
}
__device__ __forceinline__ float sigmoidf_(float x){ return 1.0f / (1.0f + __expf(-x)); }
__device__ __forceinline__ float siluf_(float x){ return x / (1.0f + __expf(-x)); }

// ---------------- weight pack into MFMA A-fragment order ----------------
__global__ __launch_bounds__(256) void pack_w_kernel(
    const float* __restrict__ Wba, const float* __restrict__ Wab, u16* __restrict__ wpack){
  int idx = blockIdx.x * 256 + threadIdx.x;      // 10 * 16384 entries
  int mat = idx >> 14;
  int r = idx & 16383;
  int j = r & 7, lane = (r >> 3) & 63, ks = (r >> 9) & 3, t = r >> 11;
  int k = ks * 32 + ((lane >> 4) << 3) + j;
  int n = t * 16 + (lane & 15);
  const float* W = (mat < 5) ? (Wba + (size_t)mat * 16384) : (Wab + (size_t)(mat - 5) * 16384);
  wpack[idx] = f2bf(W[k * 128 + n]);
}

// ---------------- fused x-side matmul: L{0,1,3,4} = x @ W{0,1,3,4} + b ----------------
__global__ __launch_bounds__(256) void xmm_kernel(
    const float* __restrict__ x, int nrows,
    const u16* __restrict__ wpackL, const float* __restrict__ bias,
    u16* __restrict__ L0, u16* __restrict__ L1, u16* __restrict__ L3, u16* __restrict__ L4){
  __shared__ u16 wlds[16384];
  const int tid = threadIdx.x;
  const int lane = tid & 63, wv = tid >> 6;
  const int g = lane >> 4;
  const long row = (long)blockIdx.x * 64 + wv * 16 + (lane & 15);
  const bool valid = row < nrows;
  const long rc = valid ? row : (long)(nrows - 1);

  s16x8 xf[4];
  {
    const float* xr = x + rc * 128 + g * 8;
    #pragma unroll
    for (int ks = 0; ks < 4; ++ks){
      float4 a = *(const float4*)(xr + ks * 32);
      float4 b = *(const float4*)(xr + ks * 32 + 4);
      s16x8 f;
      f[0]=(short)f2bf(a.x); f[1]=(short)f2bf(a.y); f[2]=(short)f2bf(a.z); f[3]=(short)f2bf(a.w);
      f[4]=(short)f2bf(b.x); f[5]=(short)f2bf(b.y); f[6]=(short)f2bf(b.z); f[7]=(short)f2bf(b.w);
      xf[ks] = f;
    }
  }
  u16* outs[4] = {L0, L1, L3, L4};
  const int mats[4] = {0, 1, 3, 4};
  #pragma unroll
  for (int mi = 0; mi < 4; ++mi){
    const int mat = mats[mi];
    __syncthreads();
    { const uint4* s = (const uint4*)(wpackL + (size_t)mat * 16384);
      uint4* d = (uint4*)wlds;
      #pragma unroll
      for (int i = 0; i < 8; ++i) d[i * 256 + tid] = s[i * 256 + tid];
    }
    __syncthreads();
    u16* Lout = outs[mi];
    #pragma unroll
    for (int t = 0; t < 8; ++t){
      f32x4 acc = {0.f, 0.f, 0.f, 0.f};
      #pragma unroll
      for (int ks = 0; ks < 4; ++ks){
        s16x8 wf = *(const s16x8*)(wlds + (t * 4 + ks) * 512 + lane * 8);
        acc = __builtin_amdgcn_mfma_f32_16x16x32_bf16(wf, xf[ks], acc, 0, 0, 0);
      }
      const int c0 = t * 16 + g * 4;
      float4 bv = *(const float4*)(bias + mat * 128 + c0);
      if (valid){
        ushort4 o;
        o.x = f2bf(acc[0] + bv.x); o.y = f2bf(acc[1] + bv.y);
        o.z = f2bf(acc[2] + bv.z); o.w = f2bf(acc[3] + bv.w);
        *(ushort4*)(Lout + row * 128 + c0) = o;
      }
    }
  }
}

// ------- y-matmul + gather L0[src]+L1[dst] -> m (bf16), no atomics -------
__global__ __launch_bounds__(256) void edge_mm_kernel(
    const float* __restrict__ y,
    const int* __restrict__ srcIdx, const int* __restrict__ dstIdx,
    const u16* __restrict__ wpack2, const float* __restrict__ bias2,
    const u16* __restrict__ L0, const u16* __restrict__ L1,
    u16* __restrict__ Mout){
  __shared__ u16 wlds[16384];
  const int tid = threadIdx.x;
  { const uint4* s = (const uint4*)wpack2;
    uint4* d = (uint4*)wlds;
    #pragma unroll
    for (int i = 0; i < 8; ++i) d[i * 256 + tid] = s[i * 256 + tid];
  }
  const int lane = tid & 63, wv = tid >> 6;
  const int g = lane >> 4;
  const int e = blockIdx.x * 64 + wv * 16 + (lane & 15);   // ne multiple of 64
  const int src = srcIdx[e];
  const int dst = dstIdx[e];
  s16x8 yf[4];
  {
    const float* yr = y + (size_t)e * 128 + g * 8;
    #pragma unroll
    for (int ks = 0; ks < 4; ++ks){
      float4 a = *(const float4*)(yr + ks * 32);
      float4 b = *(const float4*)(yr + ks * 32 + 4);
      s16x8 f;
      f[0]=(short)f2bf(a.x); f[1]=(short)f2bf(a.y); f[2]=(short)f2bf(a.z); f[3]=(short)f2bf(a.w);
      f[4]=(short)f2bf(b.x); f[5]=(short)f2bf(b.y); f[6]=(short)f2bf(b.z); f[7]=(short)f2bf(b.w);
      yf[ks] = f;
    }
  }
  __syncthreads();
  #pragma unroll
  for (int t = 0; t < 8; ++t){
    f32x4 acc = {0.f, 0.f, 0.f, 0.f};
    #pragma unroll
    for (int ks = 0; ks < 4; ++ks){
      s16x8 wf = *(const s16x8*)(wlds + (t * 4 + ks) * 512 + lane * 8);
      acc = __builtin_amdgcn_mfma_f32_16x16x32_bf16(wf, yf[ks], acc, 0, 0, 0);
    }
    const int c0 = t * 16 + g * 4;
    float4 bv = *(const float4*)(bias2 + c0);
    ushort4 l0 = *(const ushort4*)(L0 + (size_t)src * 128 + c0);
    ushort4 l1 = *(const ushort4*)(L1 + (size_t)dst * 128 + c0);
    ushort4 mo;
    mo.x = f2bf(acc[0] + bv.x + bf2f(l0.x) + bf2f(l1.x));
    mo.y = f2bf(acc[1] + bv.y + bf2f(l0.y) + bf2f(l1.y));
    mo.z = f2bf(acc[2] + bv.z + bf2f(l0.z) + bf2f(l1.z));
    mo.w = f2bf(acc[3] + bv.w + bf2f(l0.w) + bf2f(l1.w));
    *(ushort4*)(Mout + (size_t)e * 128 + c0) = mo;
  }
}

// ---------------- CSR build: histogram, 3-kernel exclusive scan, scatter ----------------
__global__ __launch_bounds__(256) void hist_kernel(
    const int* __restrict__ dstIdx, int ne, int* __restrict__ count){
  int e = blockIdx.x * 256 + threadIdx.x;
  if (e < ne) atomicAdd(&count[dstIdx[e]], 1);
}

__global__ __launch_bounds__(256) void scan1_kernel(
    const int* __restrict__ count, int n, int* __restrict__ offset, int* __restrict__ bsum){
  __shared__ int sh[256];
  const int tid = threadIdx.x;
  const int i0 = blockIdx.x * 1024 + tid * 4;
  int c0 = (i0 + 0 < n) ? count[i0 + 0] : 0;
  int c1 = (i0 + 1 < n) ? count[i0 + 1] : 0;
  int c2 = (i0 + 2 < n) ? count[i0 + 2] : 0;
  int c3 = (i0 + 3 < n) ? count[i0 + 3] : 0;
  int tsum = c0 + c1 + c2 + c3;
  sh[tid] = tsum;
  __syncthreads();
  int val = tsum;
  for (int d = 1; d < 256; d <<= 1){
    int t = (tid >= d) ? sh[tid - d] : 0;
    __syncthreads();
    val += t;
    sh[tid] = val;
    __syncthreads();
  }
  int run = val - tsum;                       // exclusive within chunk
  if (i0 + 0 < n) offset[i0 + 0] = run; run += c0;
  if (i0 + 1 < n) offset[i0 + 1] = run; run += c1;
  if (i0 + 2 < n) offset[i0 + 2] = run; run += c2;
  if (i0 + 3 < n) offset[i0 + 3] = run;
  if (tid == 255) bsum[blockIdx.x] = val;     // chunk total
}

__global__ __launch_bounds__(256) void scan2_kernel(int* __restrict__ bsum, int nb){
  __shared__ int sh[256];
  const int tid = threadIdx.x;
  int v = (tid < nb) ? bsum[tid] : 0;
  sh[tid] = v;
  __syncthreads();
  int val = v;
  for (int d = 1; d < 256; d <<= 1){
    int t = (tid >= d) ? sh[tid - d] : 0;
    __syncthreads();
    val += t;
    sh[tid] = val;
    __syncthreads();
  }
  if (tid < nb) bsum[tid] = val - v;          // exclusive
}

__global__ __launch_bounds__(256) void scan3_kernel(
    int* __restrict__ offset, int n, const int* __restrict__ bsum){
  int i = blockIdx.x * 256 + threadIdx.x;
  if (i < n) offset[i] += bsum[i >> 10];
}

__global__ __launch_bounds__(256) void scatter_kernel(
    const int* __restrict__ dstIdx, int ne, const int* __restrict__ offset,
    int* __restrict__ cursor, int* __restrict__ elist){
  int e = blockIdx.x * 256 + threadIdx.x;
  if (e < ne){
    int d = dstIdx[e];
    int p = atomicAdd(&cursor[d], 1);
    elist[offset[d] + p] = e;
  }
}

// -------- gather-side aggregation: h = L4 + num/den (fp32), fused node BN stats --------
// 32 lanes per node row; each lane owns 4 cols.
__global__ __launch_bounds__(256) void agg_kernel(
    const int* __restrict__ elist, const int* __restrict__ offset, const int* __restrict__ count,
    const int* __restrict__ srcIdx, const u16* __restrict__ M, const u16* __restrict__ L3,
    const u16* __restrict__ L4, int n, float* __restrict__ hbuf,
    float* __restrict__ sum, float* __restrict__ sumsq){
  const int tid = threadIdx.x;
  const int slot = tid >> 5, cg = tid & 31;
  float s0=0,s1=0,s2=0,s3=0, q0=0,q1=0,q2=0,q3=0;
  for (int node = blockIdx.x * 8 + slot; node < n; node += gridDim.x * 8){
    const int start = offset[node], deg = count[node];
    float n0=0,n1=0,n2=0,n3=0, d0=0,d1=0,d2=0,d3=0;
    for (int i = 0; i < deg; ++i){
      const int e = elist[start + i];
      const int src = srcIdx[e];
      ushort4 mm = *(const ushort4*)(M + (size_t)e * 128 + cg * 4);
      ushort4 l3 = *(const ushort4*)(L3 + (size_t)src * 128 + cg * 4);
      float g0 = sigmoidf_(bf2f(mm.x)), g1 = sigmoidf_(bf2f(mm.y));
      float g2 = sigmoidf_(bf2f(mm.z)), g3 = sigmoidf_(bf2f(mm.w));
      n0 += bf2f(l3.x) * g0; d0 += g0;
      n1 += bf2f(l3.y) * g1; d1 += g1;
      n2 += bf2f(l3.z) * g2; d2 += g2;
      n3 += bf2f(l3.w) * g3; d3 += g3;
    }
    ushort4 l4 = *(const ushort4*)(L4 + (size_t)node * 128 + cg * 4);
    float h0 = bf2f(l4.x) + n0 / (d0 + 1e-6f);
    float h1 = bf2f(l4.y) + n1 / (d1 + 1e-6f);
    float h2 = bf2f(l4.z) + n2 / (d2 + 1e-6f);
    float h3 = bf2f(l4.w) + n3 / (d3 + 1e-6f);
    *(float4*)(hbuf + (size_t)node * 128 + cg * 4) = make_float4(h0, h1, h2, h3);
    s0 += h0; q0 += h0*h0; s1 += h1; q1 += h1*h1;
    s2 += h2; q2 += h2*h2; s3 += h3; q3 += h3*h3;
  }
  __shared__ float sh[2048];                  // [2][8 slots][128 cols]
  sh[slot * 128 + cg * 4 + 0] = s0; sh[1024 + slot * 128 + cg * 4 + 0] = q0;
  sh[slot * 128 + cg * 4 + 1] = s1; sh[1024 + slot * 128 + cg * 4 + 1] = q1;
  sh[slot * 128 + cg * 4 + 2] = s2; sh[1024 + slot * 128 + cg * 4 + 2] = q2;
  sh[slot * 128 + cg * 4 + 3] = s3; sh[1024 + slot * 128 + cg * 4 + 3] = q3;
  __syncthreads();
  if (slot == 0){
    #pragma unroll
    for (int k = 0; k < 4; ++k){
      float S = 0, Q = 0;
      #pragma unroll
      for (int sl = 0; sl < 8; ++sl){
        S += sh[sl * 128 + cg * 4 + k];
        Q += sh[1024 + sl * 128 + cg * 4 + k];
      }
      atomicAdd(&sum[cg * 4 + k], S);
      atomicAdd(&sumsq[cg * 4 + k], Q);
    }
  }
}

// ---------------- per-column stats over bf16 matrix m ----------------
__global__ __launch_bounds__(256) void colstats_kernel(
    const u16* __restrict__ M, int rows, float* __restrict__ sum, float* __restrict__ sumsq){
  const int tid = threadIdx.x;
  const int c2 = (tid & 63) * 2, rg = tid >> 6;
  float s0=0,ss0=0,s1=0,ss1=0;
  for (long r = blockIdx.x * 4 + rg; r < rows; r += (long)gridDim.x * 4){
    ushort2 v = *(const ushort2*)(M + r * 128 + c2);
    float a = bf2f(v.x), b = bf2f(v.y);
    s0 += a; ss0 += a*a; s1 += b; ss1 += b*b;
  }
  __shared__ float sh[1024];
  sh[tid] = s0; sh[256+tid] = ss0; sh[512+tid] = s1; sh[768+tid] = ss1;
  __syncthreads();
  if (rg == 0){
    int c = tid & 63;
    float S0=0,SS0=0,S1=0,SS1=0;
    #pragma unroll
    for (int q = 0; q < 4; ++q){ int t2 = q*64 + c; S0+=sh[t2]; SS0+=sh[256+t2]; S1+=sh[512+t2]; SS1+=sh[768+t2]; }
    atomicAdd(&sum[c2], S0);   atomicAdd(&sumsq[c2], SS0);
    atomicAdd(&sum[c2+1], S1); atomicAdd(&sumsq[c2+1], SS1);
  }
}

// ---------------- out = base + silu(BN(h)) ; h fp32 ----------------
__global__ __launch_bounds__(256) void apply_f32_kernel(
    const float* __restrict__ base, const float* __restrict__ h, int n,
    const float* __restrict__ sum, const float* __restrict__ sumsq,
    const float* __restrict__ gamma, const float* __restrict__ beta,
    float* __restrict__ out){
  const int tid = threadIdx.x;
  const int c2 = (tid & 63) * 2, rg = tid >> 6;
  const float invn = 1.0f / (float)n;
  float m0 = sum[c2] * invn, m1 = sum[c2+1] * invn;
  float v0 = sumsq[c2] * invn - m0*m0, v1 = sumsq[c2+1] * invn - m1*m1;
  float sc0 = gamma[c2]   * rsqrtf(v0 + 1e-5f);
  float sc1 = gamma[c2+1] * rsqrtf(v1 + 1e-5f);
  float sh0 = beta[c2]   - m0 * sc0;
  float sh1 = beta[c2+1] - m1 * sc1;
  for (long r = blockIdx.x * 4 + rg; r < n; r += (long)gridDim.x * 4){
    const long bi = r * 128 + c2;
    float2 hv = *(const float2*)(h + bi);
    float2 xv = *(const float2*)(base + bi);
    float a = hv.x * sc0 + sh0, b = hv.y * sc1 + sh1;
    *(float2*)(out + bi) = make_float2(xv.x + siluf_(a), xv.y + siluf_(b));
  }
}

// ---------------- out = base + silu(BN(m)) ; m bf16 (in-place safe) ----------------
__global__ __launch_bounds__(256) void apply_bf16_kernel(
    const float* __restrict__ base, const u16* __restrict__ m, int n,
    const float* __restrict__ sum, const float* __restrict__ sumsq,
    const float* __restrict__ gamma, const float* __restrict__ beta,
    float* __restrict__ out){
  const int tid = threadIdx.x;
  const int c2 = (tid & 63) * 2, rg = tid >> 6;
  const float invn = 1.0f / (float)n;
  float m0 = sum[c2] * invn, m1 = sum[c2+1] * invn;
  float v0 = sumsq[c2] * invn - m0*m0, v1 = sumsq[c2+1] * invn - m1*m1;
  float sc0 = gamma[c2]   * rsqrtf(v0 + 1e-5f);
  float sc1 = gamma[c2+1] * rsqrtf(v1 + 1e-5f);
  float sh0 = beta[c2]   - m0 * sc0;
  float sh1 = beta[c2+1] - m1 * sc1;
  for (long r = blockIdx.x * 4 + rg; r < n; r += (long)gridDim.x * 4){
    const long bi = r * 128 + c2;
    ushort2 mv = *(const ushort2*)(m + bi);
    float2 xv = *(const float2*)(base + bi);
    float a = bf2f(mv.x) * sc0 + sh0, b = bf2f(mv.y) * sc1 + sh1;
    *(float2*)(out + bi) = make_float2(xv.x + siluf_(a), xv.y + siluf_(b));
  }
}

extern "C" void kernel_launch(void* const* d_in, const int* in_sizes, int n_in,
                              void* d_out, int out_size, void* d_ws, size_t ws_size,
                              hipStream_t stream){
  const float* atom = (const float*)d_in[0];
  const float* bond = (const float*)d_in[1];
  const float* trip = (const float*)d_in[2];
  const int*   eidx = (const int*)d_in[3];   // [2][E]
  const int*   aidx = (const int*)d_in[4];   // [2][A]
  const float* Wba  = (const float*)d_in[5];
  const float* bba  = (const float*)d_in[6];
  const float* bnba = (const float*)d_in[7];
  const float* Wab  = (const float*)d_in[8];
  const float* bab  = (const float*)d_in[9];
  const float* bnab = (const float*)d_in[10];

  const int N = 20000, E = 200000, A = 600000;

  float* out_atom = (float*)d_out;
  float* out_bond = out_atom + (size_t)N * 128;
  float* out_trip = out_bond + (size_t)E * 128;

  char* ws = (char*)d_ws;
  u16* wpack = (u16*)ws;                                   // 327680 B
  float* stats = (float*)(ws + 327680);                    // 4*128 f32 = 2048 B
  float* sum_e = stats, *sumsq_e = stats + 128, *sum_n = stats + 256, *sumsq_n = stats + 384;
  int* bsum   = (int*)(ws + 329728);                       // 1024 B
  int* count  = (int*)(ws + 330752);                       // 800000 B (n<=200000)
  int* offset = (int*)(ws + 1130752);                      // 800000 B
  int* cursor = (int*)(ws + 1930752);                      // 800000 B
  int* elist  = (int*)(ws + 2730752);                      // 2400000 B (ne<=600000)
  size_t off = 5130752;
  u16* L0 = (u16*)(ws + off); off += (size_t)E * 128 * 2;
  u16* L1 = (u16*)(ws + off); off += (size_t)E * 128 * 2;
  u16* L3 = (u16*)(ws + off); off += (size_t)E * 128 * 2;
  u16* L4 = (u16*)(ws + off); off += (size_t)E * 128 * 2;
  u16* M  = (u16*)(ws + off); off += (size_t)A * 128 * 2;
  float* hbuf = (float*)(ws + off);                        // E*128*4 B
  // total ws use ~444 MiB

  pack_w_kernel<<<640, 256, 0, stream>>>(Wba, Wab, wpack);

  // ---- phase 1: line graph. nodes = bonds (n=E), edges = angles (ne=A), y = trip ----
  {
    const int n = E, ne = A;
    const int* sIdx = aidx, *dIdx = aidx + A;
    hipMemsetAsync(stats, 0, 2048, stream);
    hipMemsetAsync(count, 0, (size_t)n * 4, stream);
    hipMemsetAsync(cursor, 0, (size_t)n * 4, stream);
    xmm_kernel<<<n / 64, 256, 0, stream>>>(bond, n, wpack, bba, L0, L1, L3, L4);
    hist_kernel<<<(ne + 255) / 256, 256, 0, stream>>>(dIdx, ne, count);
    scan1_kernel<<<(n + 1023) / 1024, 256, 0, stream>>>(count, n, offset, bsum);
    scan2_kernel<<<1, 256, 0, stream>>>(bsum, (n + 1023) / 1024);
    scan3_kernel<<<(n + 255) / 256, 256, 0, stream>>>(offset, n, bsum);
    scatter_kernel<<<(ne + 255) / 256, 256, 0, stream>>>(dIdx, ne, offset, cursor, elist);
    edge_mm_kernel<<<ne / 64, 256, 0, stream>>>(trip, sIdx, dIdx, wpack + 2 * 16384,
                                                bba + 256, L0, L1, M);
    colstats_kernel<<<1024, 256, 0, stream>>>(M, ne, sum_e, sumsq_e);
    agg_kernel<<<2048, 256, 0, stream>>>(elist, offset, count, sIdx, M, L3, L4, n,
                                         hbuf, sum_n, sumsq_n);
    apply_f32_kernel<<<2048, 256, 0, stream>>>(bond, hbuf, n, sum_n, sumsq_n,
                                               bnba, bnba + 128, out_bond);
    apply_bf16_kernel<<<2048, 256, 0, stream>>>(trip, M, ne, sum_e, sumsq_e,
                                                bnba + 256, bnba + 384, out_trip);
  }

  // ---- phase 2: atom graph. nodes = atoms (n=N), edges = bonds (ne=E), y = out_bond ----
  {
    const int n = N, ne = E;
    const int* sIdx = eidx, *dIdx = eidx + E;
    hipMemsetAsync(stats, 0, 2048, stream);
    hipMemsetAsync(count, 0, (size_t)n * 4, stream);
    hipMemsetAsync(cursor, 0, (size_t)n * 4, stream);
    xmm_kernel<<<(n + 63) / 64, 256, 0, stream>>>(atom, n, wpack + 5 * 16384, bab, L0, L1, L3, L4);
    hist_kernel<<<(ne + 255) / 256, 256, 0, stream>>>(dIdx, ne, count);
    scan1_kernel<<<(n + 1023) / 1024, 256, 0, stream>>>(count, n, offset, bsum);
    scan2_kernel<<<1, 256, 0, stream>>>(bsum, (n + 1023) / 1024);
    scan3_kernel<<<(n + 255) / 256, 256, 0, stream>>>(offset, n, bsum);
    scatter_kernel<<<(ne + 255) / 256, 256, 0, stream>>>(dIdx, ne, offset, cursor, elist);
    edge_mm_kernel<<<ne / 64, 256, 0, stream>>>(out_bond, sIdx, dIdx, wpack + 7 * 16384,
                                                bab + 256, L0, L1, M);
    colstats_kernel<<<1024, 256, 0, stream>>>(M, ne, sum_e, sumsq_e);
    agg_kernel<<<2048, 256, 0, stream>>>(elist, offset, count, sIdx, M, L3, L4, n,
                                         hbuf, sum_n, sumsq_n);
    apply_f32_kernel<<<2048, 256, 0, stream>>>(atom, hbuf, n, sum_n, sumsq_n,
                                               bnab, bnab + 128, out_atom);
    apply_bf16_kernel<<<2048, 256, 0, stream>>>(out_bond, M, ne, sum_e, sumsq_e,
                                                bnab + 256, bnab + 384, out_bond);
  }
}

// Round 3
// 1384.120 us; speedup vs baseline: 2.4479x; 1.0545x over previous
//
#include <hip/hip_runtime.h>
#include <hip/hip_bf16.h>

// GCPNet update: two chained edge-gated graph convs (GCAO) with training-mode BN.
// Sizes fixed per reference: N=20000 atoms, E=200000 bonds, A=600000 angles, D=128.
// R2: CSR build + gather-side aggregation (no fp32 scatter atomics).
// R3: agg edge loop batched 4-wide for MLP (was dependent-chain latency-bound,
//     12% HBM/20% VALU); h stored bf16; scan3 seeds cursor.

typedef float f32x4 __attribute__((ext_vector_type(4)));
typedef short s16x8 __attribute__((ext_vector_type(8)));
typedef unsigned short u16;

__device__ __forceinline__ u16 f2bf(float f){
  union { float f; unsigned u; } v; v.f = f;
  unsigned u = v.u;
  return (u16)((u + 0x7FFFu + ((u >> 16) & 1u)) >> 16);   // RNE
}
__device__ __forceinline__ float bf2f(u16 h){
  union { unsigned u; float f; } v; v.u = ((unsigned)h) << 16; return v.f;
}
__device__ __forceinline__ float sigmoidf_(float x){ return 1.0f / (1.0f + __expf(-x)); }
__device__ __forceinline__ float siluf_(float x){ return x / (1.0f + __expf(-x)); }

// ---------------- weight pack into MFMA A-fragment order ----------------
__global__ __launch_bounds__(256) void pack_w_kernel(
    const float* __restrict__ Wba, const float* __restrict__ Wab, u16* __restrict__ wpack){
  int idx = blockIdx.x * 256 + threadIdx.x;      // 10 * 16384 entries
  int mat = idx >> 14;
  int r = idx & 16383;
  int j = r & 7, lane = (r >> 3) & 63, ks = (r >> 9) & 3, t = r >> 11;
  int k = ks * 32 + ((lane >> 4) << 3) + j;
  int n = t * 16 + (lane & 15);
  const float* W = (mat < 5) ? (Wba + (size_t)mat * 16384) : (Wab + (size_t)(mat - 5) * 16384);
  wpack[idx] = f2bf(W[k * 128 + n]);
}

// ---------------- fused x-side matmul: L{0,1,3,4} = x @ W{0,1,3,4} + b ----------------
__global__ __launch_bounds__(256) void xmm_kernel(
    const float* __restrict__ x, int nrows,
    const u16* __restrict__ wpackL, const float* __restrict__ bias,
    u16* __restrict__ L0, u16* __restrict__ L1, u16* __restrict__ L3, u16* __restrict__ L4){
  __shared__ u16 wlds[16384];
  const int tid = threadIdx.x;
  const int lane = tid & 63, wv = tid >> 6;
  const int g = lane >> 4;
  const long row = (long)blockIdx.x * 64 + wv * 16 + (lane & 15);
  const bool valid = row < nrows;
  const long rc = valid ? row : (long)(nrows - 1);

  s16x8 xf[4];
  {
    const float* xr = x + rc * 128 + g * 8;
    #pragma unroll
    for (int ks = 0; ks < 4; ++ks){
      float4 a = *(const float4*)(xr + ks * 32);
      float4 b = *(const float4*)(xr + ks * 32 + 4);
      s16x8 f;
      f[0]=(short)f2bf(a.x); f[1]=(short)f2bf(a.y); f[2]=(short)f2bf(a.z); f[3]=(short)f2bf(a.w);
      f[4]=(short)f2bf(b.x); f[5]=(short)f2bf(b.y); f[6]=(short)f2bf(b.z); f[7]=(short)f2bf(b.w);
      xf[ks] = f;
    }
  }
  u16* outs[4] = {L0, L1, L3, L4};
  const int mats[4] = {0, 1, 3, 4};
  #pragma unroll
  for (int mi = 0; mi < 4; ++mi){
    const int mat = mats[mi];
    __syncthreads();
    { const uint4* s = (const uint4*)(wpackL + (size_t)mat * 16384);
      uint4* d = (uint4*)wlds;
      #pragma unroll
      for (int i = 0; i < 8; ++i) d[i * 256 + tid] = s[i * 256 + tid];
    }
    __syncthreads();
    u16* Lout = outs[mi];
    #pragma unroll
    for (int t = 0; t < 8; ++t){
      f32x4 acc = {0.f, 0.f, 0.f, 0.f};
      #pragma unroll
      for (int ks = 0; ks < 4; ++ks){
        s16x8 wf = *(const s16x8*)(wlds + (t * 4 + ks) * 512 + lane * 8);
        acc = __builtin_amdgcn_mfma_f32_16x16x32_bf16(wf, xf[ks], acc, 0, 0, 0);
      }
      const int c0 = t * 16 + g * 4;
      float4 bv = *(const float4*)(bias + mat * 128 + c0);
      if (valid){
        ushort4 o;
        o.x = f2bf(acc[0] + bv.x); o.y = f2bf(acc[1] + bv.y);
        o.z = f2bf(acc[2] + bv.z); o.w = f2bf(acc[3] + bv.w);
        *(ushort4*)(Lout + row * 128 + c0) = o;
      }
    }
  }
}

// ------- y-matmul + gather L0[src]+L1[dst] -> m (bf16), no atomics -------
__global__ __launch_bounds__(256) void edge_mm_kernel(
    const float* __restrict__ y,
    const int* __restrict__ srcIdx, const int* __restrict__ dstIdx,
    const u16* __restrict__ wpack2, const float* __restrict__ bias2,
    const u16* __restrict__ L0, const u16* __restrict__ L1,
    u16* __restrict__ Mout){
  __shared__ u16 wlds[16384];
  const int tid = threadIdx.x;
  { const uint4* s = (const uint4*)wpack2;
    uint4* d = (uint4*)wlds;
    #pragma unroll
    for (int i = 0; i < 8; ++i) d[i * 256 + tid] = s[i * 256 + tid];
  }
  const int lane = tid & 63, wv = tid >> 6;
  const int g = lane >> 4;
  const int e = blockIdx.x * 64 + wv * 16 + (lane & 15);   // ne multiple of 64
  const int src = srcIdx[e];
  const int dst = dstIdx[e];
  s16x8 yf[4];
  {
    const float* yr = y + (size_t)e * 128 + g * 8;
    #pragma unroll
    for (int ks = 0; ks < 4; ++ks){
      float4 a = *(const float4*)(yr + ks * 32);
      float4 b = *(const float4*)(yr + ks * 32 + 4);
      s16x8 f;
      f[0]=(short)f2bf(a.x); f[1]=(short)f2bf(a.y); f[2]=(short)f2bf(a.z); f[3]=(short)f2bf(a.w);
      f[4]=(short)f2bf(b.x); f[5]=(short)f2bf(b.y); f[6]=(short)f2bf(b.z); f[7]=(short)f2bf(b.w);
      yf[ks] = f;
    }
  }
  __syncthreads();
  #pragma unroll
  for (int t = 0; t < 8; ++t){
    f32x4 acc = {0.f, 0.f, 0.f, 0.f};
    #pragma unroll
    for (int ks = 0; ks < 4; ++ks){
      s16x8 wf = *(const s16x8*)(wlds + (t * 4 + ks) * 512 + lane * 8);
      acc = __builtin_amdgcn_mfma_f32_16x16x32_bf16(wf, yf[ks], acc, 0, 0, 0);
    }
    const int c0 = t * 16 + g * 4;
    float4 bv = *(const float4*)(bias2 + c0);
    ushort4 l0 = *(const ushort4*)(L0 + (size_t)src * 128 + c0);
    ushort4 l1 = *(const ushort4*)(L1 + (size_t)dst * 128 + c0);
    ushort4 mo;
    mo.x = f2bf(acc[0] + bv.x + bf2f(l0.x) + bf2f(l1.x));
    mo.y = f2bf(acc[1] + bv.y + bf2f(l0.y) + bf2f(l1.y));
    mo.z = f2bf(acc[2] + bv.z + bf2f(l0.z) + bf2f(l1.z));
    mo.w = f2bf(acc[3] + bv.w + bf2f(l0.w) + bf2f(l1.w));
    *(ushort4*)(Mout + (size_t)e * 128 + c0) = mo;
  }
}

// ---------------- CSR build: histogram, 3-kernel exclusive scan, scatter ----------------
__global__ __launch_bounds__(256) void hist_kernel(
    const int* __restrict__ dstIdx, int ne, int* __restrict__ count){
  int e = blockIdx.x * 256 + threadIdx.x;
  if (e < ne) atomicAdd(&count[dstIdx[e]], 1);
}

__global__ __launch_bounds__(256) void scan1_kernel(
    const int* __restrict__ count, int n, int* __restrict__ offset, int* __restrict__ bsum){
  __shared__ int sh[256];
  const int tid = threadIdx.x;
  const int i0 = blockIdx.x * 1024 + tid * 4;
  int c0 = (i0 + 0 < n) ? count[i0 + 0] : 0;
  int c1 = (i0 + 1 < n) ? count[i0 + 1] : 0;
  int c2 = (i0 + 2 < n) ? count[i0 + 2] : 0;
  int c3 = (i0 + 3 < n) ? count[i0 + 3] : 0;
  int tsum = c0 + c1 + c2 + c3;
  sh[tid] = tsum;
  __syncthreads();
  int val = tsum;
  for (int d = 1; d < 256; d <<= 1){
    int t = (tid >= d) ? sh[tid - d] : 0;
    __syncthreads();
    val += t;
    sh[tid] = val;
    __syncthreads();
  }
  int run = val - tsum;                       // exclusive within chunk
  if (i0 + 0 < n) offset[i0 + 0] = run; run += c0;
  if (i0 + 1 < n) offset[i0 + 1] = run; run += c1;
  if (i0 + 2 < n) offset[i0 + 2] = run; run += c2;
  if (i0 + 3 < n) offset[i0 + 3] = run;
  if (tid == 255) bsum[blockIdx.x] = val;     // chunk total
}

__global__ __launch_bounds__(256) void scan2_kernel(int* __restrict__ bsum, int nb){
  __shared__ int sh[256];
  const int tid = threadIdx.x;
  int v = (tid < nb) ? bsum[tid] : 0;
  sh[tid] = v;
  __syncthreads();
  int val = v;
  for (int d = 1; d < 256; d <<= 1){
    int t = (tid >= d) ? sh[tid - d] : 0;
    __syncthreads();
    val += t;
    sh[tid] = val;
    __syncthreads();
  }
  if (tid < nb) bsum[tid] = val - v;          // exclusive
}

__global__ __launch_bounds__(256) void scan3_kernel(
    int* __restrict__ offset, int n, const int* __restrict__ bsum, int* __restrict__ cursor){
  int i = blockIdx.x * 256 + threadIdx.x;
  if (i < n){
    int v = offset[i] + bsum[i >> 10];
    offset[i] = v;
    cursor[i] = v;                            // scatter cursor starts at row offset
  }
}

__global__ __launch_bounds__(256) void scatter_kernel(
    const int* __restrict__ dstIdx, int ne,
    int* __restrict__ cursor, int* __restrict__ elist){
  int e = blockIdx.x * 256 + threadIdx.x;
  if (e < ne){
    int p = atomicAdd(&cursor[dstIdx[e]], 1);
    elist[p] = e;
  }
}

// -------- gather-side aggregation: h = L4 + num/den -> bf16, fused node BN stats --------
// 32 lanes per node row; each lane owns 4 cols. Edge loop batched 4-wide for MLP.
__global__ __launch_bounds__(256) void agg_kernel(
    const int* __restrict__ elist, const int* __restrict__ offset, const int* __restrict__ count,
    const int* __restrict__ srcIdx, const u16* __restrict__ M, const u16* __restrict__ L3,
    const u16* __restrict__ L4, int n, u16* __restrict__ hbuf,
    float* __restrict__ sum, float* __restrict__ sumsq){
  const int tid = threadIdx.x;
  const int slot = tid >> 5, cg = tid & 31;
  const int c0 = cg * 4;
  float s0=0,s1=0,s2=0,s3=0, q0=0,q1=0,q2=0,q3=0;
  for (int node = blockIdx.x * 8 + slot; node < n; node += gridDim.x * 8){
    const int start = offset[node], deg = count[node];
    float n0=0,n1=0,n2=0,n3=0, d0=0,d1=0,d2=0,d3=0;
    int i = 0;
    for (; i + 4 <= deg; i += 4){
      int ee[4], ss[4];
      #pragma unroll
      for (int j = 0; j < 4; ++j) ee[j] = elist[start + i + j];
      #pragma unroll
      for (int j = 0; j < 4; ++j) ss[j] = srcIdx[ee[j]];
      ushort4 mm[4], ll[4];
      #pragma unroll
      for (int j = 0; j < 4; ++j) mm[j] = *(const ushort4*)(M + (size_t)ee[j] * 128 + c0);
      #pragma unroll
      for (int j = 0; j < 4; ++j) ll[j] = *(const ushort4*)(L3 + (size_t)ss[j] * 128 + c0);
      #pragma unroll
      for (int j = 0; j < 4; ++j){
        float g0 = sigmoidf_(bf2f(mm[j].x)), g1 = sigmoidf_(bf2f(mm[j].y));
        float g2 = sigmoidf_(bf2f(mm[j].z)), g3 = sigmoidf_(bf2f(mm[j].w));
        n0 += bf2f(ll[j].x) * g0; d0 += g0;
        n1 += bf2f(ll[j].y) * g1; d1 += g1;
        n2 += bf2f(ll[j].z) * g2; d2 += g2;
        n3 += bf2f(ll[j].w) * g3; d3 += g3;
      }
    }
    for (; i < deg; ++i){
      const int e = elist[start + i];
      const int src = srcIdx[e];
      ushort4 mm = *(const ushort4*)(M + (size_t)e * 128 + c0);
      ushort4 l3 = *(const ushort4*)(L3 + (size_t)src * 128 + c0);
      float g0 = sigmoidf_(bf2f(mm.x)), g1 = sigmoidf_(bf2f(mm.y));
      float g2 = sigmoidf_(bf2f(mm.z)), g3 = sigmoidf_(bf2f(mm.w));
      n0 += bf2f(l3.x) * g0; d0 += g0;
      n1 += bf2f(l3.y) * g1; d1 += g1;
      n2 += bf2f(l3.z) * g2; d2 += g2;
      n3 += bf2f(l3.w) * g3; d3 += g3;
    }
    ushort4 l4 = *(const ushort4*)(L4 + (size_t)node * 128 + c0);
    float h0 = bf2f(l4.x) + n0 / (d0 + 1e-6f);
    float h1 = bf2f(l4.y) + n1 / (d1 + 1e-6f);
    float h2 = bf2f(l4.z) + n2 / (d2 + 1e-6f);
    float h3 = bf2f(l4.w) + n3 / (d3 + 1e-6f);
    ushort4 ho; ho.x = f2bf(h0); ho.y = f2bf(h1); ho.z = f2bf(h2); ho.w = f2bf(h3);
    *(ushort4*)(hbuf + (size_t)node * 128 + c0) = ho;
    s0 += h0; q0 += h0*h0; s1 += h1; q1 += h1*h1;
    s2 += h2; q2 += h2*h2; s3 += h3; q3 += h3*h3;
  }
  __shared__ float sh[2048];                  // [2][8 slots][128 cols]
  sh[slot * 128 + c0 + 0] = s0; sh[1024 + slot * 128 + c0 + 0] = q0;
  sh[slot * 128 + c0 + 1] = s1; sh[1024 + slot * 128 + c0 + 1] = q1;
  sh[slot * 128 + c0 + 2] = s2; sh[1024 + slot * 128 + c0 + 2] = q2;
  sh[slot * 128 + c0 + 3] = s3; sh[1024 + slot * 128 + c0 + 3] = q3;
  __syncthreads();
  if (slot == 0){
    #pragma unroll
    for (int k = 0; k < 4; ++k){
      float S = 0, Q = 0;
      #pragma unroll
      for (int sl = 0; sl < 8; ++sl){
        S += sh[sl * 128 + c0 + k];
        Q += sh[1024 + sl * 128 + c0 + k];
      }
      atomicAdd(&sum[c0 + k], S);
      atomicAdd(&sumsq[c0 + k], Q);
    }
  }
}

// ---------------- per-column stats over bf16 matrix m ----------------
__global__ __launch_bounds__(256) void colstats_kernel(
    const u16* __restrict__ M, int rows, float* __restrict__ sum, float* __restrict__ sumsq){
  const int tid = threadIdx.x;
  const int c2 = (tid & 63) * 2, rg = tid >> 6;
  float s0=0,ss0=0,s1=0,ss1=0;
  for (long r = blockIdx.x * 4 + rg; r < rows; r += (long)gridDim.x * 4){
    ushort2 v = *(const ushort2*)(M + r * 128 + c2);
    float a = bf2f(v.x), b = bf2f(v.y);
    s0 += a; ss0 += a*a; s1 += b; ss1 += b*b;
  }
  __shared__ float sh[1024];
  sh[tid] = s0; sh[256+tid] = ss0; sh[512+tid] = s1; sh[768+tid] = ss1;
  __syncthreads();
  if (rg == 0){
    int c = tid & 63;
    float S0=0,SS0=0,S1=0,SS1=0;
    #pragma unroll
    for (int q = 0; q < 4; ++q){ int t2 = q*64 + c; S0+=sh[t2]; SS0+=sh[256+t2]; S1+=sh[512+t2]; SS1+=sh[768+t2]; }
    atomicAdd(&sum[c2], S0);   atomicAdd(&sumsq[c2], SS0);
    atomicAdd(&sum[c2+1], S1); atomicAdd(&sumsq[c2+1], SS1);
  }
}

// ---------------- out = base + silu(BN(m)) ; m bf16 (in-place safe) ----------------
__global__ __launch_bounds__(256) void apply_bf16_kernel(
    const float* __restrict__ base, const u16* __restrict__ m, int n,
    const float* __restrict__ sum, const float* __restrict__ sumsq,
    const float* __restrict__ gamma, const float* __restrict__ beta,
    float* __restrict__ out){
  const int tid = threadIdx.x;
  const int c2 = (tid & 63) * 2, rg = tid >> 6;
  const float invn = 1.0f / (float)n;
  float m0 = sum[c2] * invn, m1 = sum[c2+1] * invn;
  float v0 = sumsq[c2] * invn - m0*m0, v1 = sumsq[c2+1] * invn - m1*m1;
  float sc0 = gamma[c2]   * rsqrtf(v0 + 1e-5f);
  float sc1 = gamma[c2+1] * rsqrtf(v1 + 1e-5f);
  float sh0 = beta[c2]   - m0 * sc0;
  float sh1 = beta[c2+1] - m1 * sc1;
  for (long r = blockIdx.x * 4 + rg; r < n; r += (long)gridDim.x * 4){
    const long bi = r * 128 + c2;
    ushort2 mv = *(const ushort2*)(m + bi);
    float2 xv = *(const float2*)(base + bi);
    float a = bf2f(mv.x) * sc0 + sh0, b = bf2f(mv.y) * sc1 + sh1;
    *(float2*)(out + bi) = make_float2(xv.x + siluf_(a), xv.y + siluf_(b));
  }
}

extern "C" void kernel_launch(void* const* d_in, const int* in_sizes, int n_in,
                              void* d_out, int out_size, void* d_ws, size_t ws_size,
                              hipStream_t stream){
  const float* atom = (const float*)d_in[0];
  const float* bond = (const float*)d_in[1];
  const float* trip = (const float*)d_in[2];
  const int*   eidx = (const int*)d_in[3];   // [2][E]
  const int*   aidx = (const int*)d_in[4];   // [2][A]
  const float* Wba  = (const float*)d_in[5];
  const float* bba  = (const float*)d_in[6];
  const float* bnba = (const float*)d_in[7];
  const float* Wab  = (const float*)d_in[8];
  const float* bab  = (const float*)d_in[9];
  const float* bnab = (const float*)d_in[10];

  const int N = 20000, E = 200000, A = 600000;

  float* out_atom = (float*)d_out;
  float* out_bond = out_atom + (size_t)N * 128;
  float* out_trip = out_bond + (size_t)E * 128;

  char* ws = (char*)d_ws;
  u16* wpack = (u16*)ws;                                   // 327680 B
  float* stats = (float*)(ws + 327680);                    // 4*128 f32 = 2048 B
  float* sum_e = stats, *sumsq_e = stats + 128, *sum_n = stats + 256, *sumsq_n = stats + 384;
  int* bsum   = (int*)(ws + 329728);                       // 1024 B
  int* count  = (int*)(ws + 330752);                       // 800000 B (n<=200000)
  int* offset = (int*)(ws + 1130752);                      // 800000 B
  int* cursor = (int*)(ws + 1930752);                      // 800000 B
  int* elist  = (int*)(ws + 2730752);                      // 2400000 B (ne<=600000)
  size_t off = 5130752;
  u16* L0 = (u16*)(ws + off); off += (size_t)E * 128 * 2;
  u16* L1 = (u16*)(ws + off); off += (size_t)E * 128 * 2;
  u16* L3 = (u16*)(ws + off); off += (size_t)E * 128 * 2;
  u16* L4 = (u16*)(ws + off); off += (size_t)E * 128 * 2;
  u16* M  = (u16*)(ws + off); off += (size_t)A * 128 * 2;
  u16* hbuf = (u16*)(ws + off);                            // E*128*2 B

  pack_w_kernel<<<640, 256, 0, stream>>>(Wba, Wab, wpack);

  // ---- phase 1: line graph. nodes = bonds (n=E), edges = angles (ne=A), y = trip ----
  {
    const int n = E, ne = A;
    const int* sIdx = aidx, *dIdx = aidx + A;
    hipMemsetAsync(stats, 0, 2048, stream);
    hipMemsetAsync(count, 0, (size_t)n * 4, stream);
    xmm_kernel<<<n / 64, 256, 0, stream>>>(bond, n, wpack, bba, L0, L1, L3, L4);
    hist_kernel<<<(ne + 255) / 256, 256, 0, stream>>>(dIdx, ne, count);
    scan1_kernel<<<(n + 1023) / 1024, 256, 0, stream>>>(count, n, offset, bsum);
    scan2_kernel<<<1, 256, 0, stream>>>(bsum, (n + 1023) / 1024);
    scan3_kernel<<<(n + 255) / 256, 256, 0, stream>>>(offset, n, bsum, cursor);
    scatter_kernel<<<(ne + 255) / 256, 256, 0, stream>>>(dIdx, ne, cursor, elist);
    edge_mm_kernel<<<ne / 64, 256, 0, stream>>>(trip, sIdx, dIdx, wpack + 2 * 16384,
                                                bba + 256, L0, L1, M);
    colstats_kernel<<<1024, 256, 0, stream>>>(M, ne, sum_e, sumsq_e);
    agg_kernel<<<2048, 256, 0, stream>>>(elist, offset, count, sIdx, M, L3, L4, n,
                                         hbuf, sum_n, sumsq_n);
    apply_bf16_kernel<<<2048, 256, 0, stream>>>(bond, hbuf, n, sum_n, sumsq_n,
                                                bnba, bnba + 128, out_bond);
    apply_bf16_kernel<<<2048, 256, 0, stream>>>(trip, M, ne, sum_e, sumsq_e,
                                                bnba + 256, bnba + 384, out_trip);
  }

  // ---- phase 2: atom graph. nodes = atoms (n=N), edges = bonds (ne=E), y = out_bond ----
  {
    const int n = N, ne = E;
    const int* sIdx = eidx, *dIdx = eidx + E;
    hipMemsetAsync(stats, 0, 2048, stream);
    hipMemsetAsync(count, 0, (size_t)n * 4, stream);
    xmm_kernel<<<(n + 63) / 64, 256, 0, stream>>>(atom, n, wpack + 5 * 16384, bab, L0, L1, L3, L4);
    hist_kernel<<<(ne + 255) / 256, 256, 0, stream>>>(dIdx, ne, count);
    scan1_kernel<<<(n + 1023) / 1024, 256, 0, stream>>>(count, n, offset, bsum);
    scan2_kernel<<<1, 256, 0, stream>>>(bsum, (n + 1023) / 1024);
    scan3_kernel<<<(n + 255) / 256, 256, 0, stream>>>(offset, n, bsum, cursor);
    scatter_kernel<<<(ne + 255) / 256, 256, 0, stream>>>(dIdx, ne, cursor, elist);
    edge_mm_kernel<<<ne / 64, 256, 0, stream>>>(out_bond, sIdx, dIdx, wpack + 7 * 16384,
                                                bab + 256, L0, L1, M);
    colstats_kernel<<<1024, 256, 0, stream>>>(M, ne, sum_e, sumsq_e);
    agg_kernel<<<2048, 256, 0, stream>>>(elist, offset, count, sIdx, M, L3, L4, n,
                                         hbuf, sum_n, sumsq_n);
    apply_bf16_kernel<<<2048, 256, 0, stream>>>(atom, hbuf, n, sum_n, sumsq_n,
                                                bnab, bnab + 128, out_atom);
    apply_bf16_kernel<<<2048, 256, 0, stream>>>(out_bond, M, ne, sum_e, sumsq_e,
                                                bnab + 256, bnab + 384, out_bond);
  }
}